// Round 7
// baseline (383.991 us; speedup 1.0000x reference)
//
#include <hip/hip_runtime.h>
#include <hip/hip_bf16.h>
#include <cmath>

// PSNR + 3D-SSIM, pred/gt (N=4, C=16->D, H=512, W=512) f32.
// R7: fused (no global intermediate) + LDS-byte attack:
//     bf16-uint2 packed LDS fields (8 B/px), sliding-window H-blur
//     (4-row strips, 14 reads -> 4 outputs), 16x16 tile / 256 thr
//     (1 px/thread -> 64 f32 D-accumulators in VGPRs), 3 barriers/slice,
//     next-slice global prefetch in regs. LDS ~2.8 GB total (~41 us floor).

#define NB 4
#define DD 16
#define HH 512
#define WW 512
#define SLICE (HH * WW)
#define VOL (DD * SLICE)
#define C1F 0.0001f
#define C2F 0.0009f

#define TH 16
#define TW 16
#define SH 26          // TH+10
#define SW 26          // TW+10
#define ST 27          // uint2 row stride (pad)
#define NTHR 256
#define NIT 3          // ceil(676/256)

struct GW { float g[11]; };

__device__ inline float blo(unsigned v) {
  union { unsigned u; float f; } c; c.u = v << 16; return c.f;
}
__device__ inline float bhi(unsigned v) {
  union { unsigned u; float f; } c; c.u = v & 0xFFFF0000u; return c.f;
}
__device__ inline unsigned pack_bf2(float a, float b) {
  __hip_bfloat162 t;
  t.x = __float2bfloat16(a);
  t.y = __float2bfloat16(b);
  union { __hip_bfloat162 h; unsigned u; } c; c.h = t; return c.u;
}

__device__ inline float block_sum256(float v) {
#pragma unroll
  for (int o = 32; o > 0; o >>= 1) v += __shfl_down(v, o, 64);
  __shared__ float r[4];
  if ((threadIdx.x & 63) == 0) r[threadIdx.x >> 6] = v;
  __syncthreads();
  float out = 0.f;
  if (threadIdx.x == 0) out = r[0] + r[1] + r[2] + r[3];
  __syncthreads();
  return out;
}

__global__ void zero_acc_k(float* acc) {
  if (threadIdx.x < 8) acc[threadIdx.x] = 0.f;
}

__global__ __launch_bounds__(NTHR, 4) void fused_k(
    const float* __restrict__ pred, const float* __restrict__ gt,
    float* __restrict__ acc, GW gw) {
  __shared__ uint2 sd[SH * ST];    // staged {pk(S,D), pk(S2,D2)}  5.7 KB
  __shared__ uint2 tmp[TH * ST];   // H-blurred, same packing      3.5 KB
  __shared__ float WL[DD * DD];    // clamp-folded D-blur weights  1.0 KB
  int b = blockIdx.x;
  int tile = b & 1023;             // 32 h-tiles x 32 w-tiles
  int n = b >> 10;
  int th0 = (tile >> 5) * TH;
  int tw0 = (tile & 31) * TW;
  int t = threadIdx.x;

  if (t < DD * DD) {
    int dout = t >> 4, d = t & 15;
    float w = 0.f;
#pragma unroll
    for (int k = 0; k < 11; ++k) {
      int j = dout + k - 5; j = j < 0 ? 0 : (j > 15 ? 15 : j);
      if (j == d) w += gw.g[k];
    }
    WL[t] = w;
  }

  // stage-item metadata
  int goff[NIT], laddr[NIT];
  bool iv[NIT], own[NIT];
#pragma unroll
  for (int it = 0; it < NIT; ++it) {
    int i = t + it * NTHR;
    iv[it] = i < SH * SW;
    int ii = iv[it] ? i : 0;
    int y = ii / SW, x = ii - y * SW;
    int gy = th0 + y - 5; gy = gy < 0 ? 0 : (gy > HH - 1 ? HH - 1 : gy);
    int gx = tw0 + x - 5; gx = gx < 0 ? 0 : (gx > WW - 1 ? WW - 1 : gx);
    goff[it] = gy * WW + gx;
    laddr[it] = y * ST + x;
    own[it] = (y >= 5) && (y < 5 + TH) && (x >= 5) && (x < 5 + TW);
  }
  const float* pbase = pred + (size_t)n * VOL;
  const float* qbase = gt + (size_t)n * VOL;

  float pv[NIT], qv[NIT];
#pragma unroll
  for (int it = 0; it < NIT; ++it) {
    pv[it] = iv[it] ? pbase[goff[it]] : 0.f;
    qv[it] = iv[it] ? qbase[goff[it]] : 0.f;
  }

  float psnr = 0.f;
  float a0[DD], a1[DD], a2[DD], a3[DD];
#pragma unroll
  for (int j = 0; j < DD; ++j) { a0[j] = a1[j] = a2[j] = a3[j] = 0.f; }
  __syncthreads();   // WL visible

  int wy = t >> 4, wx = t & 15;   // this thread's output px in tile
#pragma unroll 1
  for (int d = 0; d < DD; ++d) {
    // stage slice d from prefetched regs (bf16-packed)
#pragma unroll
    for (int it = 0; it < NIT; ++it) {
      if (iv[it]) {
        float S = pv[it] + qv[it], Dm = pv[it] - qv[it];
        sd[laddr[it]] = make_uint2(pack_bf2(S, Dm), pack_bf2(S * S, Dm * Dm));
        if (own[it]) psnr = fmaf(Dm, Dm, psnr);
      }
    }
    __syncthreads();
    // prefetch slice d+1
    if (d < DD - 1) {
      const float* pd = pbase + (size_t)(d + 1) * SLICE;
      const float* qd = qbase + (size_t)(d + 1) * SLICE;
#pragma unroll
      for (int it = 0; it < NIT; ++it) {
        if (iv[it]) { pv[it] = pd[goff[it]]; qv[it] = qd[goff[it]]; }
      }
    }
    // H-blur (vertical): 4 strips of 4 rows x 26 cols = 104 items;
    // window 14 rows -> 4 outputs x 4 fields, sliding.
    if (t < 4 * SW) {
      int strip = t / SW, c = t - strip * SW;
      int r0 = strip * 4;
      float h0[4], h1[4], h2[4], h3[4];
#pragma unroll
      for (int j = 0; j < 4; ++j) { h0[j] = h1[j] = h2[j] = h3[j] = 0.f; }
#pragma unroll
      for (int k = 0; k < 14; ++k) {
        uint2 v = sd[(r0 + k) * ST + c];
        float Sv = blo(v.x), Dv = bhi(v.x), S2v = blo(v.y), D2v = bhi(v.y);
#pragma unroll
        for (int j = 0; j < 4; ++j) {
          if (k - j >= 0 && k - j <= 10) {
            float g = gw.g[k - j];
            h0[j] = fmaf(g, Sv, h0[j]);
            h1[j] = fmaf(g, Dv, h1[j]);
            h2[j] = fmaf(g, S2v, h2[j]);
            h3[j] = fmaf(g, D2v, h3[j]);
          }
        }
      }
#pragma unroll
      for (int j = 0; j < 4; ++j)
        tmp[(r0 + j) * ST + c] =
            make_uint2(pack_bf2(h0[j], h1[j]), pack_bf2(h2[j], h3[j]));
    }
    __syncthreads();
    // W-blur at (wy, wx): 11 b64 window reads; then D-accumulate.
    float w0 = 0.f, w1 = 0.f, w2 = 0.f, w3 = 0.f;
#pragma unroll
    for (int k = 0; k < 11; ++k) {
      uint2 v = tmp[wy * ST + wx + k];
      float g = gw.g[k];
      w0 = fmaf(g, blo(v.x), w0);
      w1 = fmaf(g, bhi(v.x), w1);
      w2 = fmaf(g, blo(v.y), w2);
      w3 = fmaf(g, bhi(v.y), w3);
    }
    const float* wl = WL + d;
#pragma unroll
    for (int dout = 0; dout < DD; ++dout) {
      float w = wl[dout * DD];   // broadcast LDS read
      a0[dout] = fmaf(w, w0, a0[dout]);
      a1[dout] = fmaf(w, w1, a1[dout]);
      a2[dout] = fmaf(w, w2, a2[dout]);
      a3[dout] = fmaf(w, w3, a3[dout]);
    }
    __syncthreads();   // protect sd/tmp for next slice
  }

  // SSIM over the 16 douts of this px
  float ssum = 0.f;
#pragma unroll
  for (int j = 0; j < DD; ++j) {
    float Sb = a0[j], Db = a1[j], B1 = a2[j], B2 = a3[j];
    float SS = Sb * Sb, DDm = Db * Db;
    float m12_2 = (SS - DDm) * 0.5f;     // 2*mu1*mu2
    float msq   = (SS + DDm) * 0.5f;     // mu1^2 + mu2^2
    float Epq   = (B1 - B2) * 0.25f;     // E[pq]
    float Esum  = (B1 + B2) * 0.5f;      // E[p^2+q^2]
    float sig12_2 = 2.f * Epq - m12_2;   // 2*sigma12
    float svar    = Esum - msq;          // sigma1^2 + sigma2^2
    float num = (m12_2 + C1F) * (sig12_2 + C2F);
    float den = (msq + C1F) * (svar + C2F);
    ssum += num / den;
  }
  float bs = block_sum256(ssum);
  if (t == 0) atomicAdd(&acc[4 + n], bs);
  float bp = block_sum256(psnr);
  if (t == 0) atomicAdd(&acc[n], bp);
}

__global__ void final_k(const float* __restrict__ acc, float* __restrict__ out) {
  if (threadIdx.x == 0 && blockIdx.x == 0) {
    double psnr = 0.0, ssim = 0.0;
    for (int n = 0; n < NB; ++n) {
      double mse = (double)acc[n] / (double)VOL;
      psnr += 10.0 * log10(1.0 / mse);
      ssim += (double)acc[4 + n] / (double)VOL;
    }
    out[0] = (float)psnr;
    out[1] = (float)ssim;
    out[2] = (float)NB;
  }
}

extern "C" void kernel_launch(void* const* d_in, const int* in_sizes, int n_in,
                              void* d_out, int out_size, void* d_ws, size_t ws_size,
                              hipStream_t stream) {
  const float* pred = (const float*)d_in[0];
  const float* gt = (const float*)d_in[1];
  float* acc = (float*)d_ws;    // 8 floats
  GW gw;
  double tt[11], s = 0.0;
  for (int i = 0; i < 11; ++i) {
    double x = i - 5;
    tt[i] = exp(-(x * x) / 4.5);
    s += tt[i];
  }
  for (int i = 0; i < 11; ++i) gw.g[i] = (float)(tt[i] / s);

  zero_acc_k<<<1, 64, 0, stream>>>(acc);
  fused_k<<<NB * 1024, NTHR, 0, stream>>>(pred, gt, acc, gw);
  final_k<<<1, 1, 0, stream>>>(acc, (float*)d_out);
}

// Round 8
// 271.907 us; speedup vs baseline: 1.4122x; 1.4122x over previous
//
#include <hip/hip_runtime.h>
#include <hip/hip_bf16.h>
#include <cmath>

// PSNR + 3D-SSIM, pred/gt (N=4, C=16->D, H=512, W=512) f32.
// R8 = R6 fused structure with the three measured defects fixed:
//   1) LDS fields bf16-uint2 packed (8 B/px) -> 2-way (free) bank access
//      (R6's float4 reads were 8-way: 1.04e7 conflicts);
//   2) __launch_bounds__(512,2) so 64 f32 accumulators spill to AGPRs not
//      scratch (R7's (256,4) caused 41 MB scratch writes);
//   3) sd double-buffered -> 2 barriers/slice instead of 3.
// Block = (n, 16x32 tile); loops d=0..15: stage {S,D,S2,D2} packed ->
// H-blur -> tmp -> W-blur regs -> D-accumulate via clamp-folded 16x16
// weight matrix (LDS broadcast). SSIM + PSNR fused; ws = 32 B.

#define NB 4
#define DD 16
#define HH 512
#define WW 512
#define SLICE (HH * WW)
#define VOL (DD * SLICE)
#define C1F 0.0001f
#define C2F 0.0009f

#define TH 16          // tile rows
#define TW 32          // tile cols
#define SH 26          // staged rows (TH+10)
#define SW 42          // staged cols (TW+10)
#define ST 43          // uint2 row stride (pad)
#define NTHR 512
#define NIT 3          // ceil(SH*SW=1092 / 512)

struct GW { float g[11]; };

__device__ inline float blo(unsigned v) {
  union { unsigned u; float f; } c; c.u = v << 16; return c.f;
}
__device__ inline float bhi(unsigned v) {
  union { unsigned u; float f; } c; c.u = v & 0xFFFF0000u; return c.f;
}
__device__ inline unsigned pack_bf2(float a, float b) {
  __hip_bfloat162 t;
  t.x = __float2bfloat16(a);
  t.y = __float2bfloat16(b);
  union { __hip_bfloat162 h; unsigned u; } c; c.h = t; return c.u;
}

__device__ inline float block_sum512(float v) {
#pragma unroll
  for (int o = 32; o > 0; o >>= 1) v += __shfl_down(v, o, 64);
  __shared__ float r[8];
  if ((threadIdx.x & 63) == 0) r[threadIdx.x >> 6] = v;
  __syncthreads();
  float out = 0.f;
  if (threadIdx.x == 0) {
#pragma unroll
    for (int i = 0; i < 8; ++i) out += r[i];
  }
  __syncthreads();
  return out;
}

__global__ void zero_acc_k(float* acc) {
  if (threadIdx.x < 8) acc[threadIdx.x] = 0.f;
}

__global__ __launch_bounds__(NTHR, 2) void fused_k(
    const float* __restrict__ pred, const float* __restrict__ gt,
    float* __restrict__ acc, GW gw) {
  __shared__ uint2 sd[2][SH * ST];   // staged {pk(S,D),pk(S2,D2)}  2x8.9 KB
  __shared__ uint2 tmp[TH * ST];     // H-blurred                    5.5 KB
  __shared__ float WL[DD * DD];      // clamp-folded D-blur weights  1.0 KB
  int b = blockIdx.x;
  int tile = b & 511;                // 32 h-tiles x 16 w-tiles
  int n = b >> 9;
  int th0 = (tile >> 4) * TH;
  int tw0 = (tile & 15) * TW;
  int t = threadIdx.x;

  if (t < DD * DD) {
    int dout = t >> 4, d = t & 15;
    float w = 0.f;
#pragma unroll
    for (int k = 0; k < 11; ++k) {
      int j = dout + k - 5; j = j < 0 ? 0 : (j > 15 ? 15 : j);
      if (j == d) w += gw.g[k];
    }
    WL[t] = w;
  }

  // stage-item metadata
  int goff[NIT], laddr[NIT];
  bool iv[NIT], own[NIT];
#pragma unroll
  for (int it = 0; it < NIT; ++it) {
    int i = t + it * NTHR;
    iv[it] = i < SH * SW;
    int ii = iv[it] ? i : 0;
    int y = ii / SW, x = ii - y * SW;
    int gy = th0 + y - 5; gy = gy < 0 ? 0 : (gy > HH - 1 ? HH - 1 : gy);
    int gx = tw0 + x - 5; gx = gx < 0 ? 0 : (gx > WW - 1 ? WW - 1 : gx);
    goff[it] = gy * WW + gx;
    laddr[it] = y * ST + x;
    own[it] = (y >= 5) && (y < 5 + TH) && (x >= 5) && (x < 5 + TW);
  }
  const float* pbase = pred + (size_t)n * VOL;
  const float* qbase = gt + (size_t)n * VOL;

  // prefetch slice 0
  float pv[NIT], qv[NIT];
#pragma unroll
  for (int it = 0; it < NIT; ++it) {
    pv[it] = iv[it] ? pbase[goff[it]] : 0.f;
    qv[it] = iv[it] ? qbase[goff[it]] : 0.f;
  }

  float psnr = 0.f;
  float a0[DD], a1[DD], a2[DD], a3[DD];
#pragma unroll
  for (int j = 0; j < DD; ++j) { a0[j] = a1[j] = a2[j] = a3[j] = 0.f; }
  __syncthreads();   // WL visible

  int wy = t >> 5, wx = t & 31;   // this thread's output px in tile
#pragma unroll 1
  for (int d = 0; d < DD; ++d) {
    uint2* sdb = sd[d & 1];
    // stage slice d from prefetched regs (bf16-packed); sd ping-pong means
    // no barrier is needed between last slice's W-phase and this write.
#pragma unroll
    for (int it = 0; it < NIT; ++it) {
      if (iv[it]) {
        float S = pv[it] + qv[it], Dm = pv[it] - qv[it];
        sdb[laddr[it]] = make_uint2(pack_bf2(S, Dm), pack_bf2(S * S, Dm * Dm));
        if (own[it]) psnr = fmaf(Dm, Dm, psnr);
      }
    }
    __syncthreads();   // sd ready; also guards tmp (all W-reads of d-1 done)
    // prefetch slice d+1
    if (d < DD - 1) {
      const float* pd = pbase + (size_t)(d + 1) * SLICE;
      const float* qd = qbase + (size_t)(d + 1) * SLICE;
#pragma unroll
      for (int it = 0; it < NIT; ++it) {
        if (iv[it]) { pv[it] = pd[goff[it]]; qv[it] = qd[goff[it]]; }
      }
    }
    // H-blur (vertical, 11-tap): 16 rows x 42 cols = 672 items
    for (int i = t; i < TH * SW; i += NTHR) {
      int r = i / SW, c = i - r * SW;
      float h0 = 0.f, h1 = 0.f, h2 = 0.f, h3 = 0.f;
#pragma unroll
      for (int k = 0; k < 11; ++k) {
        uint2 v = sdb[(r + k) * ST + c];
        float g = gw.g[k];
        h0 = fmaf(g, blo(v.x), h0);
        h1 = fmaf(g, bhi(v.x), h1);
        h2 = fmaf(g, blo(v.y), h2);
        h3 = fmaf(g, bhi(v.y), h3);
      }
      tmp[r * ST + c] = make_uint2(pack_bf2(h0, h1), pack_bf2(h2, h3));
    }
    __syncthreads();
    // W-blur at (wy, wx) + D-blur accumulate
    float w0 = 0.f, w1 = 0.f, w2 = 0.f, w3 = 0.f;
#pragma unroll
    for (int k = 0; k < 11; ++k) {
      uint2 v = tmp[wy * ST + wx + k];
      float g = gw.g[k];
      w0 = fmaf(g, blo(v.x), w0);
      w1 = fmaf(g, bhi(v.x), w1);
      w2 = fmaf(g, blo(v.y), w2);
      w3 = fmaf(g, bhi(v.y), w3);
    }
    const float* wl = WL + d;
#pragma unroll
    for (int dout = 0; dout < DD; ++dout) {
      float w = wl[dout * DD];   // broadcast LDS read (free)
      a0[dout] = fmaf(w, w0, a0[dout]);
      a1[dout] = fmaf(w, w1, a1[dout]);
      a2[dout] = fmaf(w, w2, a2[dout]);
      a3[dout] = fmaf(w, w3, a3[dout]);
    }
    // no trailing barrier: next stage writes sd[other buffer]; the next
    // __syncthreads after staging protects tmp.
  }

  // SSIM over the 16 douts of this px
  float ssum = 0.f;
#pragma unroll
  for (int j = 0; j < DD; ++j) {
    float Sb = a0[j], Db = a1[j], B1 = a2[j], B2 = a3[j];
    float SS = Sb * Sb, DDm = Db * Db;
    float m12_2 = (SS - DDm) * 0.5f;     // 2*mu1*mu2
    float msq   = (SS + DDm) * 0.5f;     // mu1^2 + mu2^2
    float Epq   = (B1 - B2) * 0.25f;     // E[pq]
    float Esum  = (B1 + B2) * 0.5f;      // E[p^2+q^2]
    float sig12_2 = 2.f * Epq - m12_2;   // 2*sigma12
    float svar    = Esum - msq;          // sigma1^2 + sigma2^2
    float num = (m12_2 + C1F) * (sig12_2 + C2F);
    float den = (msq + C1F) * (svar + C2F);
    ssum += num / den;
  }
  float bs = block_sum512(ssum);
  if (t == 0) atomicAdd(&acc[4 + n], bs);
  float bp = block_sum512(psnr);
  if (t == 0) atomicAdd(&acc[n], bp);
}

__global__ void final_k(const float* __restrict__ acc, float* __restrict__ out) {
  if (threadIdx.x == 0 && blockIdx.x == 0) {
    double psnr = 0.0, ssim = 0.0;
    for (int n = 0; n < NB; ++n) {
      double mse = (double)acc[n] / (double)VOL;
      psnr += 10.0 * log10(1.0 / mse);
      ssim += (double)acc[4 + n] / (double)VOL;
    }
    out[0] = (float)psnr;
    out[1] = (float)ssim;
    out[2] = (float)NB;
  }
}

extern "C" void kernel_launch(void* const* d_in, const int* in_sizes, int n_in,
                              void* d_out, int out_size, void* d_ws, size_t ws_size,
                              hipStream_t stream) {
  const float* pred = (const float*)d_in[0];
  const float* gt = (const float*)d_in[1];
  float* acc = (float*)d_ws;    // 8 floats
  GW gw;
  double tt[11], s = 0.0;
  for (int i = 0; i < 11; ++i) {
    double x = i - 5;
    tt[i] = exp(-(x * x) / 4.5);
    s += tt[i];
  }
  for (int i = 0; i < 11; ++i) gw.g[i] = (float)(tt[i] / s);

  zero_acc_k<<<1, 64, 0, stream>>>(acc);
  fused_k<<<NB * 512, NTHR, 0, stream>>>(pred, gt, acc, gw);
  final_k<<<1, 1, 0, stream>>>(acc, (float*)d_out);
}